// Round 6
// baseline (2157.271 us; speedup 1.0000x reference)
//
#include <hip/hip_runtime.h>
#include <hip/hip_fp16.h>

// NNUE forward: out = MLP(clip(concat(Wf@w_in^T+b, Bf@w_in^T+b)))
// Big GEMM: M=8192, N=256, K=40960. ~1.38 GB mandatory reads; fetch floor
// ~154us (970 MB HBM-visible at 6.3 TB/s). fp16 MFMA 16x16x32, f32 acc.
//
// v6 (from r5 post-mortem): single prefetch set = 1-interval flight ->
// exposed HBM latency each step (r4/r5 both ~3150 cyc/block-step, no pipe
// saturated). Fix: 3 register prefetch sets, tile T issued at step T-4,
// stored T-1, consumed T -> 3 barrier-intervals of flight. Raw s_barrier
// (no vmcnt drain) + compiler-counted vmcnt waits carry loads across
// barriers. Static set indexing via 6-step unrolled body (lcm(2 bufs,
// 3 sets)); 160 = 26*6 + 4 explicit tail steps.
// Geometry unchanged: BM=128 BN=256 BK=32, 512 thr (8 waves 2Mx4N),
// KS=8 -> 512 blocks (2/CU), conflict-free ((row>>1)&3)<<4 swizzle.

#define FEAT 40960
#define PSTRIDE (8192ull * 256ull)
#define KSPLIT 8
#define KCHUNK (FEAT / KSPLIT)   // 5120
#define NSTEPS (KCHUNK / 32)     // 160

using floatx4 = __attribute__((ext_vector_type(4))) float;
using half8   = __attribute__((ext_vector_type(8))) _Float16;
using half4   = __attribute__((ext_vector_type(4))) _Float16;

// Barrier that does NOT drain vmcnt: flush LDS ops, raw s_barrier.
__device__ __forceinline__ void lds_barrier() {
    asm volatile("s_waitcnt lgkmcnt(0)" ::: "memory");
    __builtin_amdgcn_s_barrier();
}

// ---------------------------------------------------------------------------
// GEMM: 512 threads = 8 waves (2M x 4N), wave tile 64x64 (acc 4x4).
// ---------------------------------------------------------------------------
template <typename PT>
__global__ __launch_bounds__(512, 4) void nnue_gemm8(
    const float* __restrict__ white, const float* __restrict__ black,
    const float* __restrict__ w_in, PT* __restrict__ P)
{
    __shared__ __align__(16) _Float16 As[2][128 * 32];   // 16 KB
    __shared__ __align__(16) _Float16 Ws[2][256 * 32];   // 32 KB

    const int tid  = threadIdx.x;
    const int lane = tid & 63;
    const int wave = tid >> 6;    // 0..7
    const int wm   = wave >> 2;   // 0..1 (M)
    const int wn   = wave & 3;    // 0..3 (N)

    const int mb = blockIdx.x & 63;
    const int ks = blockIdx.x >> 6;

    const float* Abase = (mb < 32)
        ? (white + (size_t)mb * 128 * FEAT)
        : (black + (size_t)(mb - 32) * 128 * FEAT);
    const int k0 = ks * KCHUNK;

    // staging: A tile 128x32 f32 (2 float4/thread), W 256x32 (4 float4/thread)
    const int c4    = tid & 7;               // float4 column (8 per row)
    const int row0  = tid >> 3;              // 0..63
    const int swz_w = ((row0 >> 1) & 3) << 4;
    const int woff  = (c4 * 8) ^ swz_w;

    // fragment geometry (mfma_f32_16x16x32_f16):
    // operand: lane reads row (lane&15), k-halves (lane>>4)*8..+7 (16B)
    // C/D:     row = (lane>>4)*4 + reg, col = lane&15
    const int frow  = lane & 15;
    const int fhi   = lane >> 4;
    const int swz_r = ((frow >> 1) & 3) << 4;
    const int kb    = (fhi * 16) ^ swz_r;    // byte offset within 64B row

    floatx4 acc[4][4];
    const floatx4 zero = {0.f, 0.f, 0.f, 0.f};
#pragma unroll
    for (int m = 0; m < 4; ++m)
#pragma unroll
        for (int n = 0; n < 4; ++n) acc[m][n] = zero;

    // 3 prefetch register sets (static indexing only!)
    floatx4 ra0[2], rw0[4], ra1[2], rw1[4], ra2[2], rw2[4];

    auto issue = [&](int kglob, floatx4 (&ra)[2], floatx4 (&rw)[4]) {
#pragma unroll
        for (int i = 0; i < 2; ++i)
            ra[i] = *reinterpret_cast<const floatx4*>(
                Abase + (size_t)(row0 + 64 * i) * FEAT + kglob + c4 * 4);
#pragma unroll
        for (int i = 0; i < 4; ++i)
            rw[i] = *reinterpret_cast<const floatx4*>(
                w_in + (size_t)(row0 + 64 * i) * FEAT + kglob + c4 * 4);
    };

    auto cvtStore = [&](int buf, floatx4 (&ra)[2], floatx4 (&rw)[4]) {
#pragma unroll
        for (int i = 0; i < 2; ++i) {
            half4 h;
#pragma unroll
            for (int j = 0; j < 4; ++j) h[j] = (_Float16)ra[i][j];   // RNE
            *reinterpret_cast<half4*>(
                reinterpret_cast<char*>(&As[buf][0]) + (row0 + 64 * i) * 64 + woff) = h;
        }
#pragma unroll
        for (int i = 0; i < 4; ++i) {
            half4 h;
#pragma unroll
            for (int j = 0; j < 4; ++j) h[j] = (_Float16)rw[i][j];
            *reinterpret_cast<half4*>(
                reinterpret_cast<char*>(&Ws[buf][0]) + (row0 + 64 * i) * 64 + woff) = h;
        }
    };

    auto mfmaStep = [&](int buf) {
        half8 bf[4];
#pragma unroll
        for (int n = 0; n < 4; ++n) {
            const int r = wn * 64 + n * 16 + frow;
            bf[n] = *reinterpret_cast<const half8*>(
                reinterpret_cast<const char*>(&Ws[buf][0]) + r * 64 + kb);
        }
#pragma unroll
        for (int m = 0; m < 4; ++m) {
            const int r = wm * 64 + m * 16 + frow;
            half8 af = *reinterpret_cast<const half8*>(
                reinterpret_cast<const char*>(&As[buf][0]) + r * 64 + kb);
#pragma unroll
            for (int n = 0; n < 4; ++n)
                acc[m][n] = __builtin_amdgcn_mfma_f32_16x16x32_f16(af, bf[n], acc[m][n], 0, 0, 0);
        }
    };

    // one pipeline step: mfma(tile t, buf t&1); cvtStore(tile t+1 -> buf^1,
    // from its reg set); reissue that set with tile t+4; barrier.
    auto stepf = [&](int buf, floatx4 (&ra)[2], floatx4 (&rw)[4],
                     int tcvt, int tiss) {
        mfmaStep(buf);
        if (tcvt < NSTEPS) cvtStore(buf ^ 1, ra, rw);
        if (tiss < NSTEPS) issue(k0 + tiss * 32, ra, rw);
        lds_barrier();
    };

    // prologue: tiles 0..3 in flight (0->s0, 1->s1, 2->s2, 3->s0 after cvt)
    issue(k0 +  0, ra0, rw0);
    issue(k0 + 32, ra1, rw1);
    issue(k0 + 64, ra2, rw2);
    cvtStore(0, ra0, rw0);
    issue(k0 + 96, ra0, rw0);
    lds_barrier();

    // main loop: 26 x 6 steps (t = 0..155), phases static.
    // at step t: set (t+1)%3 is consumed (tile t+1) then refilled (tile t+4).
    for (int tb = 0; tb < 156; tb += 6) {
        stepf(0, ra1, rw1, tb + 1, tb + 4);
        stepf(1, ra2, rw2, tb + 2, tb + 5);
        stepf(0, ra0, rw0, tb + 3, tb + 6);
        stepf(1, ra1, rw1, tb + 4, tb + 7);
        stepf(0, ra2, rw2, tb + 5, tb + 8);
        stepf(1, ra0, rw0, tb + 6, tb + 9);
    }
    // tail: t = 156..159 (tiles 157..159 already in flight; no new issues)
    stepf(0, ra1, rw1, 157, NSTEPS);
    stepf(1, ra2, rw2, 158, NSTEPS);
    stepf(0, ra0, rw0, 159, NSTEPS);
    mfmaStep(1);   // tile 159; no barrier needed before epilogue

    // epilogue: partial C (pre-bias, pre-clip) to workspace
    PT* Pb = P + (size_t)ks * PSTRIDE + (size_t)mb * 128 * 256;
#pragma unroll
    for (int m = 0; m < 4; ++m)
#pragma unroll
        for (int n = 0; n < 4; ++n)
#pragma unroll
            for (int r = 0; r < 4; ++r) {
                const int row = wm * 64 + m * 16 + fhi * 4 + r;
                const int col = wn * 64 + n * 16 + frow;
                Pb[(size_t)row * 256 + col] = (PT)acc[m][n][r];
            }
}

// ---------------------------------------------------------------------------
// Tail: reduce 8 K-split partials + b_in + clip -> x[.,512], then the 3 tiny
// layers. One block per 32 batch rows.
// ---------------------------------------------------------------------------
template <typename PT>
__global__ __launch_bounds__(256) void nnue_tail8(
    const PT* __restrict__ P,
    const float* __restrict__ b_in,
    const float* __restrict__ w_h1, const float* __restrict__ b_h1,
    const float* __restrict__ w_h2, const float* __restrict__ b_h2,
    const float* __restrict__ w_out, const float* __restrict__ b_out,
    float* __restrict__ out)
{
    __shared__ float xs[32][512];
    __shared__ float w1[32][513];
    __shared__ float w2[32][33];
    __shared__ float h1[32][33];
    __shared__ float h2[32][33];
    __shared__ float wo[32];

    const int tid = threadIdx.x;
    const int b0  = blockIdx.x * 32;

    for (int i = tid; i < 32 * 512; i += 256) w1[i >> 9][i & 511] = w_h1[i];
    for (int i = tid; i < 32 * 32; i += 256)  w2[i >> 5][i & 31]  = w_h2[i];
    if (tid < 32) wo[tid] = w_out[tid];

    for (int i = tid; i < 32 * 512; i += 256) {
        const int r = i >> 9, c = i & 511;
        const int persp = c >> 8, n = c & 255;
        const size_t prow = (size_t)(b0 + r) + (persp ? 4096u : 0u);
        float v = 0.f;
#pragma unroll
        for (int s = 0; s < KSPLIT; ++s)
            v += (float)P[(size_t)s * PSTRIDE + prow * 256 + n];
        v += b_in[n];
        xs[r][c] = fminf(fmaxf(v, 0.f), 1.f);
    }
    __syncthreads();

    for (int p = tid; p < 32 * 32; p += 256) {
        const int o = p & 31, r = p >> 5;
        float a = b_h1[o];
        for (int j = 0; j < 512; ++j) a += xs[r][j] * w1[o][j];
        h1[r][o] = fminf(fmaxf(a, 0.f), 1.f);
    }
    __syncthreads();

    for (int p = tid; p < 32 * 32; p += 256) {
        const int o = p & 31, r = p >> 5;
        float a = b_h2[o];
        for (int j = 0; j < 32; ++j) a += h1[r][j] * w2[o][j];
        h2[r][o] = fminf(fmaxf(a, 0.f), 1.f);
    }
    __syncthreads();

    if (tid < 32) {
        float a = b_out[0];
        for (int j = 0; j < 32; ++j) a += h2[tid][j] * wo[j];
        out[b0 + tid] = a;
    }
}

// ---------------------------------------------------------------------------
// Emergency fallback (ws too small for any split): slow but correct.
// ---------------------------------------------------------------------------
__global__ __launch_bounds__(256) void nnue_naive(
    const float* __restrict__ white, const float* __restrict__ black,
    const float* __restrict__ w_in, const float* __restrict__ b_in,
    const float* __restrict__ w_h1, const float* __restrict__ b_h1,
    const float* __restrict__ w_h2, const float* __restrict__ b_h2,
    const float* __restrict__ w_out, const float* __restrict__ b_out,
    float* __restrict__ out)
{
    __shared__ float feat[4096];
    __shared__ float xs[512];
    __shared__ float h1s[32];
    __shared__ float h2s[32];
    const int b = blockIdx.x, tid = threadIdx.x;
    float acc0 = 0.f, acc1 = 0.f;
    for (int c = 0; c < FEAT; c += 2048) {
        for (int i = tid; i < 2048; i += 256) {
            feat[i]        = white[(size_t)b * FEAT + c + i];
            feat[2048 + i] = black[(size_t)b * FEAT + c + i];
        }
        __syncthreads();
        const float* wr = w_in + (size_t)tid * FEAT + c;
        for (int k = 0; k < 2048; ++k) {
            const float w = wr[k];
            acc0 += feat[k] * w;
            acc1 += feat[2048 + k] * w;
        }
        __syncthreads();
    }
    xs[tid]       = fminf(fmaxf(acc0 + b_in[tid], 0.f), 1.f);
    xs[256 + tid] = fminf(fmaxf(acc1 + b_in[tid], 0.f), 1.f);
    __syncthreads();
    if (tid < 32) {
        float a = b_h1[tid];
        for (int j = 0; j < 512; ++j) a += xs[j] * w_h1[tid * 512 + j];
        h1s[tid] = fminf(fmaxf(a, 0.f), 1.f);
    }
    __syncthreads();
    if (tid < 32) {
        float a = b_h2[tid];
        for (int j = 0; j < 32; ++j) a += h1s[j] * w_h2[tid * 32 + j];
        h2s[tid] = fminf(fmaxf(a, 0.f), 1.f);
    }
    __syncthreads();
    if (tid == 0) {
        float a = b_out[0];
        for (int j = 0; j < 32; ++j) a += h2s[j] * w_out[j];
        out[b] = a;
    }
}

extern "C" void kernel_launch(void* const* d_in, const int* in_sizes, int n_in,
                              void* d_out, int out_size, void* d_ws, size_t ws_size,
                              hipStream_t stream)
{
    const float* white = (const float*)d_in[0];
    const float* black = (const float*)d_in[1];
    const float* w_in  = (const float*)d_in[2];
    const float* b_in  = (const float*)d_in[3];
    const float* w_h1  = (const float*)d_in[4];
    const float* b_h1  = (const float*)d_in[5];
    const float* w_h2  = (const float*)d_in[6];
    const float* b_h2  = (const float*)d_in[7];
    const float* w_out = (const float*)d_in[8];
    const float* b_out = (const float*)d_in[9];
    float* out = (float*)d_out;

    const size_t f32Need = KSPLIT * PSTRIDE * sizeof(float);     // 64 MB
    const size_t f16Need = KSPLIT * PSTRIDE * sizeof(_Float16);  // 32 MB

    if (ws_size >= f32Need) {
        float* P = (float*)d_ws;
        nnue_gemm8<float><<<dim3(64 * KSPLIT), 512, 0, stream>>>(white, black, w_in, P);
        nnue_tail8<float><<<dim3(128), 256, 0, stream>>>(P, b_in, w_h1, b_h1,
                                                         w_h2, b_h2, w_out, b_out, out);
    } else if (ws_size >= f16Need) {
        _Float16* P = (_Float16*)d_ws;
        nnue_gemm8<_Float16><<<dim3(64 * KSPLIT), 512, 0, stream>>>(white, black, w_in, P);
        nnue_tail8<_Float16><<<dim3(128), 256, 0, stream>>>(P, b_in, w_h1, b_h1,
                                                            w_h2, b_h2, w_out, b_out, out);
    } else {
        nnue_naive<<<4096, 256, 0, stream>>>(white, black, w_in, b_in, w_h1, b_h1,
                                             w_h2, b_h2, w_out, b_out, out);
    }
}

// Round 9
// 382.418 us; speedup vs baseline: 5.6411x; 5.6411x over previous
//
#include <hip/hip_runtime.h>
#include <hip/hip_fp16.h>

// NNUE forward: out = MLP(clip(concat(Wf@w_in^T+b, Bf@w_in^T+b)))
// Big GEMM: M=8192, N=256, K=40960, memory-bound on the 1.31 GB A stream.
// fp16 MFMA 16x16x32, f32 accumulate.
//
// v7b (r7/r8 were infra failures: container died before source push; no
// compile/run happened either round. Source re-audited for hang safety:
// fixed-trip loops, uniform barriers, bounded global_load_lds addresses.
// Resubmitted unchanged.)
//
// Design (from r6 post-mortem: reg budget is EXACTLY 128, any extra spills):
//  - W pre-converted to f16 in ws, pre-swizzled into the exact LDS tile image
//    (16 KB per K-step); GEMM stages W via global_load_lds width=16 -> zero
//    VGPR, zero VALU for W.
//  - A: 2 reg prefetch sets (16 VGPR), 2-step flight.
//  - LDS: A dbuf 16KB + W 3-buf 48KB = 64KB, 2 blocks/CU.
//  - per step: issueW ; mfma ; cvtStoreA ; issueA ; s_waitcnt vmcnt(6)
//    lgkmcnt(0) ; raw s_barrier.  vmcnt(6) leaves {A(t+2),W(t+2),A(t+3)} in
//    flight => W(t+1)/A(t+1) complete at each barrier (FIFO, W-before-A order
//    pinned by sched_barrier).
//  - blockIdx&7 = ks -> one K-slice per XCD: W chunk (2.6 MB) L2-resident.

#define FEAT 40960
#define PSTRIDE (8192ull * 256ull)
#define KSPLIT 8
#define KCHUNK (FEAT / KSPLIT)   // 5120
#define NSTEPS (KCHUNK / 32)     // 160
#define WTILE_BYTES 16384        // 256 rows x 32 k x f16, swizzled
#define WWS_BYTES (1280ull * WTILE_BYTES)

using floatx4 = __attribute__((ext_vector_type(4))) float;
using half8   = __attribute__((ext_vector_type(8))) _Float16;
using half4   = __attribute__((ext_vector_type(4))) _Float16;

__device__ __forceinline__ void lds_barrier() {
    asm volatile("s_waitcnt lgkmcnt(0)" ::: "memory");
    __builtin_amdgcn_s_barrier();
    __builtin_amdgcn_sched_barrier(0);
}

// ---------------------------------------------------------------------------
// W pre-pass: w_in f32 [256][40960] -> Wws f16, 1280 chunks of 16 KB, each
// the exact (swizzled) LDS image for one K-step: byte(r, granule g) =
// T*16384 + r*64 + ((g ^ ((r>>1)&3))*16), granule = 8 consecutive k-halves.
// ---------------------------------------------------------------------------
__global__ __launch_bounds__(256) void nnue_wprep(
    const float* __restrict__ w_in, _Float16* __restrict__ Wws)
{
    const int bid = blockIdx.x;                       // 1280
    const int T   = (bid & 7) * NSTEPS + (bid >> 3);  // ks in low bits -> XCD
    char* base = (char*)Wws + (size_t)T * WTILE_BYTES;
    const int tid = threadIdx.x;
    const int kg0 = T * 32;
#pragma unroll
    for (int i = 0; i < 4; ++i) {
        const int G = tid + i * 256;                  // 0..1023
        const int r = G >> 2, g = G & 3;
        const float* src = w_in + (size_t)r * FEAT + kg0 + g * 8;
        floatx4 v0 = *reinterpret_cast<const floatx4*>(src);
        floatx4 v1 = *reinterpret_cast<const floatx4*>(src + 4);
        half8 h;
#pragma unroll
        for (int j = 0; j < 4; ++j) { h[j] = (_Float16)v0[j]; h[4 + j] = (_Float16)v1[j]; }
        *reinterpret_cast<half8*>(base + r * 64 + ((g ^ ((r >> 1) & 3)) << 4)) = h;
    }
}

// ---------------------------------------------------------------------------
// Primary GEMM: BM=128 BN=256 BK=32, 512 thr (8 waves 2Mx4N, wave tile 64x64).
// ---------------------------------------------------------------------------
template <typename PT>
__global__ __launch_bounds__(512, 4) void nnue_gemm_v7(
    const float* __restrict__ white, const float* __restrict__ black,
    const _Float16* __restrict__ Wws, PT* __restrict__ P)
{
    __shared__ __align__(16) _Float16 As[2][128 * 32];   // 16 KB
    __shared__ __align__(16) _Float16 Ws[3][256 * 32];   // 48 KB

    const int tid  = threadIdx.x;
    const int lane = tid & 63;
    const int wave = tid >> 6;
    const int wm   = wave >> 2;   // 0..1 (M)
    const int wn   = wave & 3;    // 0..3 (N)

    const int ks = blockIdx.x & 7;    // XCD-aligned K-split
    const int mb = blockIdx.x >> 3;   // 0..63

    const float* Abase = (mb < 32)
        ? (white + (size_t)mb * 128 * FEAT)
        : (black + (size_t)(mb - 32) * 128 * FEAT);
    const int k0 = ks * KCHUNK;

    // A staging: 128x32 f32 tile = 1024 float4, 2/thread
    const int c4    = tid & 7;
    const int row0  = tid >> 3;
    const int woff  = (c4 * 8) ^ (((row0 >> 1) & 3) << 4);

    // fragment geometry (mfma_f32_16x16x32_f16)
    const int frow  = lane & 15;
    const int fhi   = lane >> 4;
    const int kb    = (fhi * 16) ^ (((frow >> 1) & 3) << 4);

    // W async staging: per-lane global src, wave-uniform LDS segment
    const char* wsrc0 = (const char*)Wws + (size_t)(ks * NSTEPS) * WTILE_BYTES
                        + wave * 2048 + lane * 16;

    floatx4 acc[4][4];
    const floatx4 zero = {0.f, 0.f, 0.f, 0.f};
#pragma unroll
    for (int m = 0; m < 4; ++m)
#pragma unroll
        for (int n = 0; n < 4; ++n) acc[m][n] = zero;

    floatx4 ra0[2], ra1[2];

    auto issueA = [&](int kglob, floatx4 (&ra)[2]) {
#pragma unroll
        for (int i = 0; i < 2; ++i)
            ra[i] = *reinterpret_cast<const floatx4*>(
                Abase + (size_t)(row0 + 64 * i) * FEAT + kglob + c4 * 4);
    };

    auto issueW = [&](int t, int wb) {
        const char* g = wsrc0 + (size_t)t * WTILE_BYTES;
        char* l = (char*)&Ws[wb][0] + wave * 2048;
        __builtin_amdgcn_global_load_lds(
            (const __attribute__((address_space(1))) unsigned int*)g,
            (__attribute__((address_space(3))) unsigned int*)l, 16, 0, 0);
        __builtin_amdgcn_global_load_lds(
            (const __attribute__((address_space(1))) unsigned int*)(g + 1024),
            (__attribute__((address_space(3))) unsigned int*)(l + 1024), 16, 0, 0);
    };

    auto cvtStoreA = [&](int ab, floatx4 (&ra)[2]) {
#pragma unroll
        for (int i = 0; i < 2; ++i) {
            half4 h;
#pragma unroll
            for (int j = 0; j < 4; ++j) h[j] = (_Float16)ra[i][j];   // RNE
            *reinterpret_cast<half4*>(
                reinterpret_cast<char*>(&As[ab][0]) + (row0 + 64 * i) * 64 + woff) = h;
        }
    };

    auto mfmaStep = [&](int ab, int wb) {
        half8 bf[4];
#pragma unroll
        for (int n = 0; n < 4; ++n) {
            const int r = wn * 64 + n * 16 + frow;
            bf[n] = *reinterpret_cast<const half8*>(
                reinterpret_cast<const char*>(&Ws[wb][0]) + r * 64 + kb);
        }
#pragma unroll
        for (int m = 0; m < 4; ++m) {
            const int r = wm * 64 + m * 16 + frow;
            half8 af = *reinterpret_cast<const half8*>(
                reinterpret_cast<const char*>(&As[ab][0]) + r * 64 + kb);
#pragma unroll
            for (int n = 0; n < 4; ++n)
                acc[m][n] = __builtin_amdgcn_mfma_f32_16x16x32_f16(af, bf[n], acc[m][n], 0, 0, 0);
        }
    };

    // one steady-state step (all buffer/set indices compile-time):
    auto stepf = [&](int t, int abR, int abW, int wbR, int wbW, floatx4 (&ra)[2]) {
        issueW(t + 2, wbW);                    // W first in vmem FIFO
        __builtin_amdgcn_sched_barrier(0);     // pin W-before-A issue order
        mfmaStep(abR, wbR);
        cvtStoreA(abW, ra);                    // consumes A(t+1), waits counted vmcnt
        issueA(k0 + (t + 3) * 32, ra);         // refill same set with A(t+3)
        asm volatile("s_waitcnt vmcnt(6) lgkmcnt(0)" ::: "memory");
        __builtin_amdgcn_s_barrier();
        __builtin_amdgcn_sched_barrier(0);
    };

    // prologue: W(0),W(1) in flight; A(0),A(1) in flight; tile0 staged
    issueW(0, 0);
    issueW(1, 1);
    __builtin_amdgcn_sched_barrier(0);
    issueA(k0, ra0);
    issueA(k0 + 32, ra1);
    cvtStoreA(0, ra0);        // waits A(0); forces W(0),W(1) (older in FIFO)
    issueA(k0 + 64, ra0);     // A(2)
    lds_barrier();

    // main loop: t = 0..155 (26 x 6, lcm(2 A-bufs/sets, 3 W-bufs))
    for (int t = 0; t < 156; t += 6) {
        stepf(t + 0, 0, 1, 0, 2, ra1);
        stepf(t + 1, 1, 0, 1, 0, ra0);
        stepf(t + 2, 0, 1, 2, 1, ra1);
        stepf(t + 3, 1, 0, 0, 2, ra0);
        stepf(t + 4, 0, 1, 1, 0, ra1);
        stepf(t + 5, 1, 0, 2, 1, ra0);
    }
    stepf(156, 0, 1, 0, 2, ra1);   // still full body: issues W(158), A(159)

    // t = 157
    issueW(159, 0);
    __builtin_amdgcn_sched_barrier(0);
    mfmaStep(1, 1);
    cvtStoreA(0, ra0);             // A(158)
    asm volatile("s_waitcnt vmcnt(4) lgkmcnt(0)" ::: "memory");  // W(158) done
    __builtin_amdgcn_s_barrier();
    __builtin_amdgcn_sched_barrier(0);
    // t = 158
    mfmaStep(0, 2);
    cvtStoreA(1, ra1);             // A(159)
    asm volatile("s_waitcnt vmcnt(0) lgkmcnt(0)" ::: "memory");  // W(159) done
    __builtin_amdgcn_s_barrier();
    __builtin_amdgcn_sched_barrier(0);
    // t = 159
    mfmaStep(1, 0);

    // epilogue: partial C (pre-bias, pre-clip) to workspace
    PT* Pb = P + (size_t)ks * PSTRIDE + (size_t)mb * 128 * 256;
#pragma unroll
    for (int m = 0; m < 4; ++m)
#pragma unroll
        for (int n = 0; n < 4; ++n)
#pragma unroll
            for (int r = 0; r < 4; ++r) {
                const int row = wm * 64 + m * 16 + fhi * 4 + r;
                const int col = wn * 64 + n * 16 + frow;
                Pb[(size_t)row * 256 + col] = (PT)acc[m][n][r];
            }
}

// ---------------------------------------------------------------------------
// Fallback GEMM (r5 path, proven): reg-staged W, single A/W prefetch set.
// ---------------------------------------------------------------------------
template <typename PT>
__global__ __launch_bounds__(512, 4) void nnue_gemm8(
    const float* __restrict__ white, const float* __restrict__ black,
    const float* __restrict__ w_in, PT* __restrict__ P)
{
    __shared__ __align__(16) _Float16 As[2][128 * 32];
    __shared__ __align__(16) _Float16 Ws[2][256 * 32];

    const int tid  = threadIdx.x;
    const int lane = tid & 63;
    const int wave = tid >> 6;
    const int wm   = wave >> 2;
    const int wn   = wave & 3;

    const int mb = blockIdx.x & 63;
    const int ks = blockIdx.x >> 6;

    const float* Abase = (mb < 32)
        ? (white + (size_t)mb * 128 * FEAT)
        : (black + (size_t)(mb - 32) * 128 * FEAT);
    const int k0 = ks * KCHUNK;

    const int c4    = tid & 7;
    const int row0  = tid >> 3;
    const int swz_w = ((row0 >> 1) & 3) << 4;
    const int woff  = (c4 * 8) ^ swz_w;
    const int frow  = lane & 15;
    const int fhi   = lane >> 4;
    const int kb    = (fhi * 16) ^ (((frow >> 1) & 3) << 4);

    floatx4 acc[4][4];
    const floatx4 zero = {0.f, 0.f, 0.f, 0.f};
#pragma unroll
    for (int m = 0; m < 4; ++m)
#pragma unroll
        for (int n = 0; n < 4; ++n) acc[m][n] = zero;

    floatx4 ra[2], rw[4];

    auto issue = [&](int kglob) {
#pragma unroll
        for (int i = 0; i < 2; ++i)
            ra[i] = *reinterpret_cast<const floatx4*>(
                Abase + (size_t)(row0 + 64 * i) * FEAT + kglob + c4 * 4);
#pragma unroll
        for (int i = 0; i < 4; ++i)
            rw[i] = *reinterpret_cast<const floatx4*>(
                w_in + (size_t)(row0 + 64 * i) * FEAT + kglob + c4 * 4);
    };

    auto cvtStore = [&](int buf) {
#pragma unroll
        for (int i = 0; i < 2; ++i) {
            half4 h;
#pragma unroll
            for (int j = 0; j < 4; ++j) h[j] = (_Float16)ra[i][j];
            *reinterpret_cast<half4*>(
                reinterpret_cast<char*>(&As[buf][0]) + (row0 + 64 * i) * 64 + woff) = h;
        }
#pragma unroll
        for (int i = 0; i < 4; ++i) {
            half4 h;
#pragma unroll
            for (int j = 0; j < 4; ++j) h[j] = (_Float16)rw[i][j];
            *reinterpret_cast<half4*>(
                reinterpret_cast<char*>(&Ws[buf][0]) + (row0 + 64 * i) * 64 + woff) = h;
        }
    };

    auto mfmaStep = [&](int buf) {
        half8 bf[4];
#pragma unroll
        for (int n = 0; n < 4; ++n) {
            const int r = wn * 64 + n * 16 + frow;
            bf[n] = *reinterpret_cast<const half8*>(
                reinterpret_cast<const char*>(&Ws[buf][0]) + r * 64 + kb);
        }
#pragma unroll
        for (int m = 0; m < 4; ++m) {
            const int r = wm * 64 + m * 16 + frow;
            half8 af = *reinterpret_cast<const half8*>(
                reinterpret_cast<const char*>(&As[buf][0]) + r * 64 + kb);
#pragma unroll
            for (int n = 0; n < 4; ++n)
                acc[m][n] = __builtin_amdgcn_mfma_f32_16x16x32_f16(af, bf[n], acc[m][n], 0, 0, 0);
        }
    };

    issue(k0);
    cvtStore(0);
    issue(k0 + 32);
    lds_barrier();

    for (int t = 0; t < NSTEPS; ++t) {
        mfmaStep(t & 1);
        if (t + 1 < NSTEPS) {
            cvtStore((t + 1) & 1);
            if (t + 2 < NSTEPS) issue(k0 + (t + 2) * 32);
        }
        lds_barrier();
    }

    PT* Pb = P + (size_t)ks * PSTRIDE + (size_t)mb * 128 * 256;
#pragma unroll
    for (int m = 0; m < 4; ++m)
#pragma unroll
        for (int n = 0; n < 4; ++n)
#pragma unroll
            for (int r = 0; r < 4; ++r) {
                const int row = wm * 64 + m * 16 + fhi * 4 + r;
                const int col = wn * 64 + n * 16 + frow;
                Pb[(size_t)row * 256 + col] = (PT)acc[m][n][r];
            }
}

// ---------------------------------------------------------------------------
// Tail: reduce 8 K-split partials + b_in + clip -> x[.,512], then the 3 tiny
// layers. One block per 32 batch rows.
// ---------------------------------------------------------------------------
template <typename PT>
__global__ __launch_bounds__(256) void nnue_tail8(
    const PT* __restrict__ P,
    const float* __restrict__ b_in,
    const float* __restrict__ w_h1, const float* __restrict__ b_h1,
    const float* __restrict__ w_h2, const float* __restrict__ b_h2,
    const float* __restrict__ w_out, const float* __restrict__ b_out,
    float* __restrict__ out)
{
    __shared__ float xs[32][512];
    __shared__ float w1[32][513];
    __shared__ float w2[32][33];
    __shared__ float h1[32][33];
    __shared__ float h2[32][33];
    __shared__ float wo[32];

    const int tid = threadIdx.x;
    const int b0  = blockIdx.x * 32;

    for (int i = tid; i < 32 * 512; i += 256) w1[i >> 9][i & 511] = w_h1[i];
    for (int i = tid; i < 32 * 32; i += 256)  w2[i >> 5][i & 31]  = w_h2[i];
    if (tid < 32) wo[tid] = w_out[tid];

    for (int i = tid; i < 32 * 512; i += 256) {
        const int r = i >> 9, c = i & 511;
        const int persp = c >> 8, n = c & 255;
        const size_t prow = (size_t)(b0 + r) + (persp ? 4096u : 0u);
        float v = 0.f;
#pragma unroll
        for (int s = 0; s < KSPLIT; ++s)
            v += (float)P[(size_t)s * PSTRIDE + prow * 256 + n];
        v += b_in[n];
        xs[r][c] = fminf(fmaxf(v, 0.f), 1.f);
    }
    __syncthreads();

    for (int p = tid; p < 32 * 32; p += 256) {
        const int o = p & 31, r = p >> 5;
        float a = b_h1[o];
        for (int j = 0; j < 512; ++j) a += xs[r][j] * w1[o][j];
        h1[r][o] = fminf(fmaxf(a, 0.f), 1.f);
    }
    __syncthreads();

    for (int p = tid; p < 32 * 32; p += 256) {
        const int o = p & 31, r = p >> 5;
        float a = b_h2[o];
        for (int j = 0; j < 32; ++j) a += h1[r][j] * w2[o][j];
        h2[r][o] = fminf(fmaxf(a, 0.f), 1.f);
    }
    __syncthreads();

    if (tid < 32) {
        float a = b_out[0];
        for (int j = 0; j < 32; ++j) a += h2[tid][j] * wo[j];
        out[b0 + tid] = a;
    }
}

// ---------------------------------------------------------------------------
// Emergency fallback (ws too small for any split): slow but correct.
// ---------------------------------------------------------------------------
__global__ __launch_bounds__(256) void nnue_naive(
    const float* __restrict__ white, const float* __restrict__ black,
    const float* __restrict__ w_in, const float* __restrict__ b_in,
    const float* __restrict__ w_h1, const float* __restrict__ b_h1,
    const float* __restrict__ w_h2, const float* __restrict__ b_h2,
    const float* __restrict__ w_out, const float* __restrict__ b_out,
    float* __restrict__ out)
{
    __shared__ float feat[4096];
    __shared__ float xs[512];
    __shared__ float h1s[32];
    __shared__ float h2s[32];
    const int b = blockIdx.x, tid = threadIdx.x;
    float acc0 = 0.f, acc1 = 0.f;
    for (int c = 0; c < FEAT; c += 2048) {
        for (int i = tid; i < 2048; i += 256) {
            feat[i]        = white[(size_t)b * FEAT + c + i];
            feat[2048 + i] = black[(size_t)b * FEAT + c + i];
        }
        __syncthreads();
        const float* wr = w_in + (size_t)tid * FEAT + c;
        for (int k = 0; k < 2048; ++k) {
            const float w = wr[k];
            acc0 += feat[k] * w;
            acc1 += feat[2048 + k] * w;
        }
        __syncthreads();
    }
    xs[tid]       = fminf(fmaxf(acc0 + b_in[tid], 0.f), 1.f);
    xs[256 + tid] = fminf(fmaxf(acc1 + b_in[tid], 0.f), 1.f);
    __syncthreads();
    if (tid < 32) {
        float a = b_h1[tid];
        for (int j = 0; j < 512; ++j) a += xs[j] * w_h1[tid * 512 + j];
        h1s[tid] = fminf(fmaxf(a, 0.f), 1.f);
    }
    __syncthreads();
    if (tid < 32) {
        float a = b_h2[tid];
        for (int j = 0; j < 32; ++j) a += h1s[j] * w_h2[tid * 32 + j];
        h2s[tid] = fminf(fmaxf(a, 0.f), 1.f);
    }
    __syncthreads();
    if (tid == 0) {
        float a = b_out[0];
        for (int j = 0; j < 32; ++j) a += h2s[j] * w_out[j];
        out[b] = a;
    }
}

extern "C" void kernel_launch(void* const* d_in, const int* in_sizes, int n_in,
                              void* d_out, int out_size, void* d_ws, size_t ws_size,
                              hipStream_t stream)
{
    const float* white = (const float*)d_in[0];
    const float* black = (const float*)d_in[1];
    const float* w_in  = (const float*)d_in[2];
    const float* b_in  = (const float*)d_in[3];
    const float* w_h1  = (const float*)d_in[4];
    const float* b_h1  = (const float*)d_in[5];
    const float* w_h2  = (const float*)d_in[6];
    const float* b_h2  = (const float*)d_in[7];
    const float* w_out = (const float*)d_in[8];
    const float* b_out = (const float*)d_in[9];
    float* out = (float*)d_out;

    const size_t pF32 = KSPLIT * PSTRIDE * sizeof(float);     // 64 MB
    const size_t pF16 = KSPLIT * PSTRIDE * sizeof(_Float16);  // 32 MB

    if (ws_size >= pF32 + WWS_BYTES) {
        float* P = (float*)d_ws;
        _Float16* Wws = (_Float16*)((char*)d_ws + pF32);
        nnue_wprep<<<dim3(1280), 256, 0, stream>>>(w_in, Wws);
        nnue_gemm_v7<float><<<dim3(512), 512, 0, stream>>>(white, black, Wws, P);
        nnue_tail8<float><<<dim3(128), 256, 0, stream>>>(P, b_in, w_h1, b_h1,
                                                         w_h2, b_h2, w_out, b_out, out);
    } else if (ws_size >= pF16 + WWS_BYTES) {
        _Float16* P = (_Float16*)d_ws;
        _Float16* Wws = (_Float16*)((char*)d_ws + pF16);
        nnue_wprep<<<dim3(1280), 256, 0, stream>>>(w_in, Wws);
        nnue_gemm_v7<_Float16><<<dim3(512), 512, 0, stream>>>(white, black, Wws, P);
        nnue_tail8<_Float16><<<dim3(128), 256, 0, stream>>>(P, b_in, w_h1, b_h1,
                                                            w_h2, b_h2, w_out, b_out, out);
    } else if (ws_size >= pF32) {
        float* P = (float*)d_ws;
        nnue_gemm8<float><<<dim3(512), 512, 0, stream>>>(white, black, w_in, P);
        nnue_tail8<float><<<dim3(128), 256, 0, stream>>>(P, b_in, w_h1, b_h1,
                                                         w_h2, b_h2, w_out, b_out, out);
    } else if (ws_size >= pF16) {
        _Float16* P = (_Float16*)d_ws;
        nnue_gemm8<_Float16><<<dim3(512), 512, 0, stream>>>(white, black, w_in, P);
        nnue_tail8<_Float16><<<dim3(128), 256, 0, stream>>>(P, b_in, w_h1, b_h1,
                                                            w_h2, b_h2, w_out, b_out, out);
    } else {
        nnue_naive<<<4096, 256, 0, stream>>>(white, black, w_in, b_in, w_h1, b_h1,
                                             w_h2, b_h2, w_out, b_out, out);
    }
}